// Round 7
// baseline (540.732 us; speedup 1.0000x reference)
//
#include <hip/hip_runtime.h>
#include <stdint.h>

#define NTOK   4096
#define DMODEL 1024
#define HFF    4096
#define NEXP   8
#define BM     128
#define BN     128
#define BK     64
#define MAX_MT 71            // max sum_e ceil(cnt_e/128), sum cnt = 8192
#define KT1    (DMODEL/BK)   // 16
#define KT2    (HFF/BK)      // 64

typedef unsigned int   u32;
typedef unsigned short u16;
typedef u32   u32x4  __attribute__((ext_vector_type(4)));
typedef short s16x8  __attribute__((ext_vector_type(8)));
typedef float f32x4  __attribute__((ext_vector_type(4)));

__device__ __forceinline__ u16 f2bf(float f) {
  u32 u = __builtin_bit_cast(u32, f);
  return (u16)((u + 0x7FFFu + ((u >> 16) & 1u)) >> 16);   // RNE, finite inputs
}
__device__ __forceinline__ float bf2f(u32 lo16) {
  return __builtin_bit_cast(float, lo16 << 16);
}

// async global->LDS, 16B per lane; LDS dest = wave-uniform base + lane*16
__device__ __forceinline__ void gld_lds16(const void* g, void* l) {
  __builtin_amdgcn_global_load_lds((const __attribute__((address_space(1))) void*)g,
                                   (__attribute__((address_space(3))) void*)l, 16, 0, 0);
}

// ------- W [K][N] fp32 -> 16x16x32-fragment-ordered bf16 images (16KB/tile) ----
// Image entry g*64+l, g=(k>>5)*8+(n>>4), l=((k>>3)&3)*16+(n&15), elem j = k&7:
//   W[kt*64 + (g>>3)*32 + (l>>4)*8 + j][nt*128 + (g&7)*16 + (l&15)]
__global__ __launch_bounds__(256) void k_prearrange(
    const float* __restrict__ W, u32x4* __restrict__ Bp, int K, int N, int NT, int KT) {
  int tile = blockIdx.x;             // (e*NT + nt)*KT + kt
  int kt  = tile % KT; int rem = tile / KT;
  int nt  = rem % NT;  int e   = rem / NT;
  __shared__ u32x4 img4[1024];
  u16* img = (u16*)img4;
  const int tid = threadIdx.x;
  const float* src = W + ((size_t)e * K + (size_t)kt * BK) * N + (size_t)nt * BN;
  const int n4 = (tid & 31) * 4;
  const int k0 = tid >> 5;
#pragma unroll
  for (int p = 0; p < 8; ++p) {
    const int k = k0 + p * 8;
    float4 v = *(const float4*)(src + (size_t)k * N + n4);
    u16 b[4] = { f2bf(v.x), f2bf(v.y), f2bf(v.z), f2bf(v.w) };
#pragma unroll
    for (int q = 0; q < 4; ++q) {
      const int n = n4 + q;
      const int idx16 = ((k >> 5) * 8 + (n >> 4)) * 64 + ((k >> 3) & 3) * 16 + (n & 15);
      img[idx16 * 8 + (k & 7)] = b[q];
    }
  }
  __syncthreads();
  u32x4* outp = Bp + (size_t)tile * 1024;
#pragma unroll
  for (int c = 0; c < 4; ++c) outp[c * 256 + tid] = img4[c * 256 + tid];
}

// ---- A images: gather tokens (fp32 x) -> fragment-ordered bf16 images --------
__global__ __launch_bounds__(256) void k_arrange_a(
    const float* __restrict__ x, const int* __restrict__ tok_of_slot,
    const int* __restrict__ mtile_e, u32x4* __restrict__ Ap) {
  const int bid = blockIdx.x;
  const int mt = bid / KT1, kt = bid % KT1;
  if (mtile_e[mt] < 0) return;
  __shared__ u32x4 img[1024];
  u16* imgu = (u16*)img;
  const int tid = threadIdx.x;
  const int lane16 = tid & 15, rp = tid >> 4;
#pragma unroll
  for (int p = 0; p < 8; ++p) {
    const int row = rp + p * 16;
    const int tok = tok_of_slot[mt * BM + row];
    float4 v = *(const float4*)(x + (size_t)tok * DMODEL + kt * BK + lane16 * 4);
    const int g = (lane16 >> 3) * 8 + (row >> 4);
    const int l = ((lane16 >> 1) & 3) * 16 + (row & 15);
    u16* dst = imgu + (size_t)(g * 64 + l) * 8 + (lane16 & 1) * 4;
    dst[0] = f2bf(v.x); dst[1] = f2bf(v.y); dst[2] = f2bf(v.z); dst[3] = f2bf(v.w);
  }
  __syncthreads();
  u32x4* outp = Ap + (size_t)bid * 1024;
#pragma unroll
  for (int c = 0; c < 4; ++c) outp[c * 256 + tid] = img[c * 256 + tid];
}

// ---------------- gating: logits, top-2, softmax(2), counts ----------------
__global__ void k_gating(const float* __restrict__ x, const float* __restrict__ Wg,
                         const float* __restrict__ bg, int* __restrict__ top_idx,
                         float* __restrict__ top_w, int* __restrict__ counts) {
  int t = blockIdx.x, tid = threadIdx.x;
  float acc[NEXP];
#pragma unroll
  for (int e = 0; e < NEXP; ++e) acc[e] = 0.f;
  const float* xr = x + (size_t)t * DMODEL;
  for (int d = tid; d < DMODEL; d += 256) {
    float xv = xr[d];
    const float4* wg = (const float4*)(Wg + d * NEXP);
    float4 a = wg[0], b = wg[1];
    acc[0] += xv * a.x; acc[1] += xv * a.y; acc[2] += xv * a.z; acc[3] += xv * a.w;
    acc[4] += xv * b.x; acc[5] += xv * b.y; acc[6] += xv * b.z; acc[7] += xv * b.w;
  }
#pragma unroll
  for (int e = 0; e < NEXP; ++e)
#pragma unroll
    for (int off = 32; off; off >>= 1) acc[e] += __shfl_down(acc[e], off);
  __shared__ float red[4][NEXP];
  int w = tid >> 6;
  if ((tid & 63) == 0)
    for (int e = 0; e < NEXP; ++e) red[w][e] = acc[e];
  __syncthreads();
  if (tid == 0) {
    float v0 = -1e30f, v1 = -1e30f; int i0 = 0, i1 = 0;
    for (int e = 0; e < NEXP; ++e) {
      float l = red[0][e] + red[1][e] + red[2][e] + red[3][e] + bg[e];
      if (l > v0)      { v1 = v0; i1 = i0; v0 = l; i0 = e; }
      else if (l > v1) { v1 = l; i1 = e; }
    }
    float e1 = expf(v1 - v0);
    float w0 = 1.f / (1.f + e1);
    top_idx[2 * t] = i0; top_idx[2 * t + 1] = i1;
    top_w[2 * t] = w0;   top_w[2 * t + 1] = e1 * w0;
    atomicAdd(&counts[i0], 1); atomicAdd(&counts[i1], 1);
  }
}

// ------------ padded prefix offsets + compact live m-tile map ------------
__global__ void k_offsets(const int* __restrict__ counts, int* __restrict__ poffset,
                          int* __restrict__ mtile_e) {
  if (threadIdx.x == 0 && blockIdx.x == 0) {
    int off = 0, nm = 0;
    for (int e = 0; e < NEXP; ++e) {
      poffset[e] = off;
      int nt = (counts[e] + BM - 1) / BM;
      for (int lt = 0; lt < nt; ++lt) { mtile_e[nm] = e; ++nm; }
      off += nt * BM;
    }
    for (; nm < MAX_MT; ++nm) mtile_e[nm] = -1;
  }
}

// ---------------- scatter tokens to expert slots ----------------
__global__ void k_scatter(const int* __restrict__ top_idx, const int* __restrict__ poffset,
                          int* __restrict__ cursor, int* __restrict__ tok_of_slot,
                          int* __restrict__ token_slot) {
  int t = blockIdx.x * 256 + threadIdx.x;
  if (t >= NTOK) return;
  for (int k = 0; k < 2; ++k) {
    int e = top_idx[2 * t + k];
    int p = atomicAdd(&cursor[e], 1);
    int slot = poffset[e] + p;
    tok_of_slot[slot] = t;
    token_slot[2 * t + k] = slot;
  }
}

// ---------------- grouped GEMM: C = act(A @ B + bias) ----------------
// Both operands are fragment-ordered images; staging = pure linear 1KB
// global_load_lds per instruction. m97 structure: 128x128xBK64, 4 waves,
// 16x16x32 MFMA, acc[4][4]/wave, 32KB single-buffer LDS, 2 barriers/K-step.
// Epilogue: swizzled-LDS staging -> coalesced writes.
//   MODE 1: GELU; write h as GEMM2 A-images (kt2 = nt*2, nt*2+1).
//   MODE 0: no act; write row-major rows (coalesced 256B chunks).
template <int MODE>
__global__ __launch_bounds__(256) void k_gemm(
    const u32x4* __restrict__ Ap, const u32x4* __restrict__ Bp,
    const float* __restrict__ bias, int Nfull, int NT, int KT,
    const int* __restrict__ mtile_e, u16* __restrict__ Cout, int c_stride) {
  const u32 nwg  = gridDim.x;
  const u32 orig = blockIdx.x;
  const u32 gsw  = (orig & 7u) * (nwg >> 3) + (orig >> 3);  // XCD chunks, mt-fastest
  const int mt = (int)(gsw % MAX_MT);
  const int nt = (int)(gsw / MAX_MT);

  const int e = mtile_e[mt];
  if (e < 0) return;

  __shared__ u32x4 As[2048];         // 32KB: A images [0,1024), B images [1024,2048)
  u32x4* Bs = As + 1024;

  const int tid  = threadIdx.x;
  const int lane = tid & 63;
  const int wv   = tid >> 6;
  const int wm   = wv >> 1;
  const int wn   = wv & 1;

  const u32x4* aptr = Ap + (size_t)mt * KT * 1024 + wv * 256 + lane;
  const u32x4* bptr = Bp + (size_t)(e * NT + nt) * KT * 1024 + wv * 256 + lane;

  f32x4 acc[4][4] = {};

  for (int kt = 0; kt < KT; ++kt) {
#pragma unroll
    for (int c = 0; c < 4; ++c)
      gld_lds16(aptr + (size_t)kt * 1024 + c * 64, &As[(wv * 4 + c) * 64]);
#pragma unroll
    for (int c = 0; c < 4; ++c)
      gld_lds16(bptr + (size_t)kt * 1024 + c * 64, &Bs[(wv * 4 + c) * 64]);
    __syncthreads();                 // images complete (vmcnt drained)
#pragma unroll
    for (int k32 = 0; k32 < 2; ++k32) {
      s16x8 a[4], b[4];
#pragma unroll
      for (int mi = 0; mi < 4; ++mi)
        a[mi] = __builtin_bit_cast(s16x8, As[(k32 * 8 + wm * 4 + mi) * 64 + lane]);
#pragma unroll
      for (int ni = 0; ni < 4; ++ni)
        b[ni] = __builtin_bit_cast(s16x8, Bs[(k32 * 8 + wn * 4 + ni) * 64 + lane]);
#pragma unroll
      for (int mi = 0; mi < 4; ++mi)
#pragma unroll
        for (int ni = 0; ni < 4; ++ni)
          acc[mi][ni] = __builtin_amdgcn_mfma_f32_16x16x32_bf16(a[mi], b[ni], acc[mi][ni], 0, 0, 0);
    }
    __syncthreads();                 // reads done before next overwrite
  }

  // ---- epilogue: bias(+GELU)+f2bf into swizzled LDS tile, then coalesced out.
  // LDS tile: u16 cimg[row][128], physical chunk = (col>>3) ^ (row&7).
  u16* cimg = (u16*)As;
  const int rbase = (lane >> 4) * 4;
  const int col16 = lane & 15;
#pragma unroll
  for (int ni = 0; ni < 4; ++ni) {
    const int ncl = wn * 64 + ni * 16 + col16;
    const float bv = bias[(size_t)e * Nfull + nt * BN + ncl];
#pragma unroll
    for (int mi = 0; mi < 4; ++mi) {
#pragma unroll
      for (int r = 0; r < 4; ++r) {
        const int rowl = wm * 64 + mi * 16 + rbase + r;
        float v = acc[mi][ni][r] + bv;
        if (MODE) v = 0.5f * v * (1.0f + erff(v * 0.70710678118654752f));
        cimg[rowl * 128 + (((ncl >> 3) ^ (rowl & 7)) << 3) + (ncl & 7)] = f2bf(v);
      }
    }
  }
  __syncthreads();
  if (MODE) {
    // write two GEMM2 A-images (kt2 = nt*2+kk), linear 1KB per instruction
    u32x4* outp = (u32x4*)Cout + ((size_t)mt * KT2 + nt * 2) * 1024;
#pragma unroll
    for (int c = 0; c < 8; ++c) {
      const int idx = c * 256 + tid;
      const int kk = idx >> 10, gg = (idx >> 6) & 15, l = idx & 63;
      const int row = (gg & 7) * 16 + (l & 15);
      const int chunk = kk * 8 + (gg >> 3) * 4 + (l >> 4);
      u32x4 v = *(const u32x4*)&cimg[row * 128 + ((chunk ^ (row & 7)) << 3)];
      outp[(size_t)kk * 1024 + gg * 64 + l] = v;
    }
  } else {
    // row-major: 16 lanes write one row's 256B contiguously
#pragma unroll
    for (int c = 0; c < 8; ++c) {
      const int cid = c * 256 + tid;
      const int row = cid >> 4, chunk = cid & 15;
      u32x4 v = *(const u32x4*)&cimg[row * 128 + ((chunk ^ (row & 7)) << 3)];
      *(u32x4*)&Cout[(size_t)(mt * BM + row) * c_stride + nt * BN + chunk * 8] = v;
    }
  }
}

// ---------------- combine (top-2 weighted) + residual + LayerNorm ----------------
__global__ void k_combine_ln(const float* __restrict__ x, const u16* __restrict__ y,
                             const int* __restrict__ token_slot, const float* __restrict__ top_w,
                             const float* __restrict__ gamma, const float* __restrict__ beta,
                             float* __restrict__ out) {
  int t = blockIdx.x, tid = threadIdx.x;
  int s0 = token_slot[2 * t], s1 = token_slot[2 * t + 1];
  float w0 = top_w[2 * t], w1 = top_w[2 * t + 1];
  float4 xv = ((const float4*)(x + (size_t)t * DMODEL))[tid];
  uint2 a = ((const uint2*)(y + (size_t)s0 * DMODEL))[tid];
  uint2 b = ((const uint2*)(y + (size_t)s1 * DMODEL))[tid];
  float r0 = xv.x + w0 * bf2f(a.x & 0xffffu) + w1 * bf2f(b.x & 0xffffu);
  float r1 = xv.y + w0 * bf2f(a.x >> 16)     + w1 * bf2f(b.x >> 16);
  float r2 = xv.z + w0 * bf2f(a.y & 0xffffu) + w1 * bf2f(b.y & 0xffffu);
  float r3 = xv.w + w0 * bf2f(a.y >> 16)     + w1 * bf2f(b.y >> 16);
  float s  = r0 + r1 + r2 + r3;
  float sq = r0 * r0 + r1 * r1 + r2 * r2 + r3 * r3;
#pragma unroll
  for (int off = 32; off; off >>= 1) { s += __shfl_down(s, off); sq += __shfl_down(sq, off); }
  __shared__ float rs[4], rq[4];
  __shared__ float mu_s, rsig_s;
  int w = tid >> 6;
  if ((tid & 63) == 0) { rs[w] = s; rq[w] = sq; }
  __syncthreads();
  if (tid == 0) {
    float S = rs[0] + rs[1] + rs[2] + rs[3];
    float Q = rq[0] + rq[1] + rq[2] + rq[3];
    float mu  = S * (1.0f / DMODEL);
    float var = Q * (1.0f / DMODEL) - mu * mu;
    mu_s = mu; rsig_s = rsqrtf(var + 1e-5f);
  }
  __syncthreads();
  float mu = mu_s, rsig = rsig_s;
  float4 gv = ((const float4*)gamma)[tid];
  float4 bv = ((const float4*)beta)[tid];
  float4 o;
  o.x = (r0 - mu) * rsig * gv.x + bv.x;
  o.y = (r1 - mu) * rsig * gv.y + bv.y;
  o.z = (r2 - mu) * rsig * gv.z + bv.z;
  o.w = (r3 - mu) * rsig * gv.w + bv.w;
  ((float4*)(out + (size_t)t * DMODEL))[tid] = o;
}

// ---------------- launch ----------------
extern "C" void kernel_launch(void* const* d_in, const int* in_sizes, int n_in,
                              void* d_out, int out_size, void* d_ws, size_t ws_size,
                              hipStream_t stream) {
  const float* x     = (const float*)d_in[0];
  const float* Wg    = (const float*)d_in[1];
  const float* bg    = (const float*)d_in[2];
  const float* W1    = (const float*)d_in[3];
  const float* b1    = (const float*)d_in[4];
  const float* W2    = (const float*)d_in[5];
  const float* b2    = (const float*)d_in[6];
  const float* gamma = (const float*)d_in[7];
  const float* beta  = (const float*)d_in[8];
  float* out = (float*)d_out;

  // workspace (~180 MB): Bp2 aliases [Ap1|Bp1] (written after GEMM1 is done)
  char* ws = (char*)d_ws;
  const size_t szAp1 = (size_t)MAX_MT * KT1 * 1024 * 16;   // 18.6 MB
  const size_t szBp1 = (size_t)NEXP * DMODEL * HFF * 2;    // 67.1 MB
  u32x4* Ap1 = (u32x4*)ws;
  u32x4* Bp1 = (u32x4*)(ws + szAp1);
  u32x4* Bp2 = (u32x4*)ws;                                  // alias
  char* p = ws + szAp1 + szBp1;
  u32x4* hImg = (u32x4*)p; p += (size_t)MAX_MT * KT2 * 1024 * 16;   // 74.4 MB
  u16*   yb   = (u16*)p;   p += (size_t)MAX_MT * BM * DMODEL * 2;   // 18.6 MB
  int*   meta = (int*)p;
  int*   counts      = meta;
  int*   cursor      = counts + 8;
  int*   poffset     = cursor + 8;
  int*   tok_of_slot = poffset + 8;
  int*   mtile_e     = tok_of_slot + MAX_MT * BM;
  int*   token_slot  = mtile_e + MAX_MT;
  int*   top_idx     = token_slot + 2 * NTOK;
  float* top_w       = (float*)(top_idx + 2 * NTOK);
  (void)ws_size; (void)in_sizes; (void)n_in; (void)out_size;

  // zero counts/cursor/poffset + tok_of_slot (pad rows -> token 0)
  hipMemsetAsync(meta, 0, (size_t)(24 + MAX_MT * BM) * 4, stream);

  k_gating<<<NTOK, 256, 0, stream>>>(x, Wg, bg, top_idx, top_w, counts);
  k_offsets<<<1, 1, 0, stream>>>(counts, poffset, mtile_e);
  k_scatter<<<NTOK / 256, 256, 0, stream>>>(top_idx, poffset, cursor, tok_of_slot, token_slot);

  // W1 [8][1024][4096] -> Bp1 (NT=32, KT=16)
  k_prearrange<<<NEXP * (HFF / BN) * KT1, 256, 0, stream>>>(W1, Bp1, DMODEL, HFF, HFF / BN, KT1);
  // gathered token images
  k_arrange_a<<<MAX_MT * KT1, 256, 0, stream>>>(x, tok_of_slot, mtile_e, Ap1);

  // GEMM1: 32 nt x 71 mt = 2272 blocks (8*284); GELU; writes h as A-images
  k_gemm<1><<<(HFF / BN) * MAX_MT, 256, 0, stream>>>(
      Ap1, Bp1, b1, HFF, HFF / BN, KT1, mtile_e, (u16*)hImg, 0);

  // W2 [8][4096][1024] -> Bp2 (NT=8, KT=64) — after GEMM1 (aliases Ap1/Bp1)
  k_prearrange<<<NEXP * (DMODEL / BN) * KT2, 256, 0, stream>>>(W2, Bp2, HFF, DMODEL, DMODEL / BN, KT2);

  // GEMM2: 8 nt x 71 mt = 568 blocks (8*71); writes yb row-major
  k_gemm<0><<<(DMODEL / BN) * MAX_MT, 256, 0, stream>>>(
      hImg, Bp2, b2, DMODEL, DMODEL / BN, KT2, mtile_e, yb, DMODEL);

  k_combine_ln<<<NTOK, 256, 0, stream>>>(x, yb, token_slot, top_w, gamma, beta, out);
}

// Round 8
// 484.841 us; speedup vs baseline: 1.1153x; 1.1153x over previous
//
#include <hip/hip_runtime.h>
#include <stdint.h>

#define NTOK   4096
#define DMODEL 1024
#define HFF    4096
#define NEXP   8
#define BM     256
#define BK     64
#define MAX_MT 40            // max sum_e ceil(cnt_e/256) = 39 given sum cnt = 8192
#define KT1    (DMODEL/BK)   // 16
#define KT2    (HFF/BK)      // 64

typedef unsigned int   u32;
typedef unsigned short u16;
typedef u32   u32x4  __attribute__((ext_vector_type(4)));
typedef short s16x8  __attribute__((ext_vector_type(8)));
typedef float f32x4  __attribute__((ext_vector_type(4)));

__device__ __forceinline__ u16 f2bf(float f) {
  u32 u = __builtin_bit_cast(u32, f);
  return (u16)((u + 0x7FFFu + ((u >> 16) & 1u)) >> 16);   // RNE, finite inputs
}
__device__ __forceinline__ float bf2f(u32 lo16) {
  return __builtin_bit_cast(float, lo16 << 16);
}

// async global->LDS, 16B per lane; LDS dest = wave-uniform base + lane*16
__device__ __forceinline__ void gld_lds16(const void* g, void* l) {
  __builtin_amdgcn_global_load_lds((const __attribute__((address_space(1))) void*)g,
                                   (__attribute__((address_space(3))) void*)l, 16, 0, 0);
}

// ---- fragment-image format (per 64k x 256n tile, 2048 u32x4 = 32KB) ----------
// entry g*64+l: g = (k>>5)*16 + (n>>4), l = ((k>>3)&3)*16 + (n&15), elem j = k&7
// holds  T[k][n]  (T = W slab or token slab). Half k32 = entries [k32*1024,+1024).

// ------- W [K][N] fp32 -> fragment images, 256-col tiles -----------------------
__global__ __launch_bounds__(256) void k_prearrange(
    const float* __restrict__ W, u32x4* __restrict__ Bp, int K, int N, int NT, int KT) {
  int tile = blockIdx.x;             // (e*NT + nt)*KT + kt
  int kt  = tile % KT; int rem = tile / KT;
  int nt  = rem % NT;  int e   = rem / NT;
  __shared__ u32x4 img4[2048];       // 32KB
  u16* img = (u16*)img4;
  const int tid = threadIdx.x;
  const float* src = W + ((size_t)e * K + (size_t)kt * BK) * N + (size_t)nt * 256;
  const int c4 = (tid & 63) * 4;     // n: 0,4,...,252
  const int k0 = tid >> 6;           // 0..3
#pragma unroll
  for (int p = 0; p < 16; ++p) {
    const int k = k0 + p * 4;
    float4 v = *(const float4*)(src + (size_t)k * N + c4);
    u16 b[4] = { f2bf(v.x), f2bf(v.y), f2bf(v.z), f2bf(v.w) };
#pragma unroll
    for (int q = 0; q < 4; ++q) {
      const int n = c4 + q;
      const int ent = ((k >> 5) * 16 + (n >> 4)) * 64 + ((k >> 3) & 3) * 16 + (n & 15);
      img[ent * 8 + (k & 7)] = b[q];
    }
  }
  __syncthreads();
  u32x4* outp = Bp + (size_t)tile * 2048;
#pragma unroll
  for (int c = 0; c < 8; ++c) outp[c * 256 + tid] = img4[c * 256 + tid];
}

// ---- A images: gather tokens (fp32 x) -> fragment images (256-row tiles) ------
__global__ __launch_bounds__(256) void k_arrange_a(
    const float* __restrict__ x, const int* __restrict__ tok_of_slot,
    const int* __restrict__ mtile_e, u32x4* __restrict__ Ap) {
  const int bid = blockIdx.x;
  const int mt = bid / KT1, kt = bid % KT1;
  if (mtile_e[mt] < 0) return;
  __shared__ u32x4 img[2048];        // 32KB
  u16* imgu = (u16*)img;
  const int tid = threadIdx.x;
  const int lane16 = tid & 15, rp = tid >> 4;
#pragma unroll
  for (int p = 0; p < 16; ++p) {
    const int row = rp + p * 16;
    const int tok = tok_of_slot[mt * BM + row];
    float4 v = *(const float4*)(x + (size_t)tok * DMODEL + kt * BK + lane16 * 4);
    const int g = (lane16 >> 3) * 16 + (row >> 4);
    const int l = ((lane16 >> 1) & 3) * 16 + (row & 15);
    u16* dst = imgu + (size_t)(g * 64 + l) * 8 + (lane16 & 1) * 4;
    dst[0] = f2bf(v.x); dst[1] = f2bf(v.y); dst[2] = f2bf(v.z); dst[3] = f2bf(v.w);
  }
  __syncthreads();
  u32x4* outp = Ap + (size_t)bid * 2048;
#pragma unroll
  for (int c = 0; c < 8; ++c) outp[c * 256 + tid] = img[c * 256 + tid];
}

// ---------------- gating: logits, top-2, softmax(2), counts ----------------
__global__ void k_gating(const float* __restrict__ x, const float* __restrict__ Wg,
                         const float* __restrict__ bg, int* __restrict__ top_idx,
                         float* __restrict__ top_w, int* __restrict__ counts) {
  int t = blockIdx.x, tid = threadIdx.x;
  float acc[NEXP];
#pragma unroll
  for (int e = 0; e < NEXP; ++e) acc[e] = 0.f;
  const float* xr = x + (size_t)t * DMODEL;
  for (int d = tid; d < DMODEL; d += 256) {
    float xv = xr[d];
    const float4* wg = (const float4*)(Wg + d * NEXP);
    float4 a = wg[0], b = wg[1];
    acc[0] += xv * a.x; acc[1] += xv * a.y; acc[2] += xv * a.z; acc[3] += xv * a.w;
    acc[4] += xv * b.x; acc[5] += xv * b.y; acc[6] += xv * b.z; acc[7] += xv * b.w;
  }
#pragma unroll
  for (int e = 0; e < NEXP; ++e)
#pragma unroll
    for (int off = 32; off; off >>= 1) acc[e] += __shfl_down(acc[e], off);
  __shared__ float red[4][NEXP];
  int w = tid >> 6;
  if ((tid & 63) == 0)
    for (int e = 0; e < NEXP; ++e) red[w][e] = acc[e];
  __syncthreads();
  if (tid == 0) {
    float v0 = -1e30f, v1 = -1e30f; int i0 = 0, i1 = 0;
    for (int e = 0; e < NEXP; ++e) {
      float l = red[0][e] + red[1][e] + red[2][e] + red[3][e] + bg[e];
      if (l > v0)      { v1 = v0; i1 = i0; v0 = l; i0 = e; }
      else if (l > v1) { v1 = l; i1 = e; }
    }
    float e1 = expf(v1 - v0);
    float w0 = 1.f / (1.f + e1);
    top_idx[2 * t] = i0; top_idx[2 * t + 1] = i1;
    top_w[2 * t] = w0;   top_w[2 * t + 1] = e1 * w0;
    atomicAdd(&counts[i0], 1); atomicAdd(&counts[i1], 1);
  }
}

// ------------ padded prefix offsets + compact live m-tile map ------------
__global__ void k_offsets(const int* __restrict__ counts, int* __restrict__ poffset,
                          int* __restrict__ mtile_e) {
  if (threadIdx.x == 0 && blockIdx.x == 0) {
    int off = 0, nm = 0;
    for (int e = 0; e < NEXP; ++e) {
      poffset[e] = off;
      int nt = (counts[e] + BM - 1) / BM;
      for (int lt = 0; lt < nt; ++lt) { mtile_e[nm] = e; ++nm; }
      off += nt * BM;
    }
    for (; nm < MAX_MT; ++nm) mtile_e[nm] = -1;
  }
}

// ---------------- scatter tokens to expert slots ----------------
__global__ void k_scatter(const int* __restrict__ top_idx, const int* __restrict__ poffset,
                          int* __restrict__ cursor, int* __restrict__ tok_of_slot,
                          int* __restrict__ token_slot) {
  int t = blockIdx.x * 256 + threadIdx.x;
  if (t >= NTOK) return;
  for (int k = 0; k < 2; ++k) {
    int e = top_idx[2 * t + k];
    int p = atomicAdd(&cursor[e], 1);
    int slot = poffset[e] + p;
    tok_of_slot[slot] = t;
    token_slot[2 * t + k] = slot;
  }
}

// ---------------- grouped GEMM, m201-style ring schedule ----------------
// 256x256xBK64 tile, 512 threads / 8 waves (2M x 4N), acc[8][4] per wave.
// 4-deep half-K-slab ring per operand (16KB slabs, 128KB LDS total).
// Per half H: counted s_waitcnt vmcnt(8) (drains slab H, keeps H+1,H+2 in
// flight) -> raw s_barrier -> {stage 2 A-loads of H+3 | ds_read b[4],a[0..3] |
// 16 MFMA @prio1} -> {stage 2 B-loads | ds_read a[4..7] | 16 MFMA @prio1}.
// MODE 1: GELU epilogue, writes h directly as GEMM2 A-images (4 x 32KB).
// MODE 0: plain epilogue, row-major C via XOR-swizzled LDS staging.
template <int MODE>
__global__ __launch_bounds__(512, 2) void k_gemm(
    const u32x4* __restrict__ Ap, const u32x4* __restrict__ Bp,
    const float* __restrict__ bias, int Nfull, int NT, int KT,
    const int* __restrict__ mtile_e, u16* __restrict__ Cout) {
  const u32 nwg  = gridDim.x;
  const u32 orig = blockIdx.x;
  const u32 gsw  = (orig & 7u) * (nwg >> 3) + (orig >> 3);  // XCD chunks
  const int mt = (int)(gsw % MAX_MT);                        // mt-fastest
  const int nt = (int)(gsw / MAX_MT);
  const int e = mtile_e[mt];
  if (e < 0) return;

  __shared__ u32x4 LB[8192];          // 128KB; A ring [0,4096), B ring [4096,8192)
  u32x4* AsR = LB;
  u32x4* BsR = LB + 4096;

  const int tid  = threadIdx.x;
  const int lane = tid & 63;
  const int wv   = tid >> 6;          // 0..7
  const int wm   = wv >> 2;           // 0..1
  const int wn   = wv & 3;            // 0..3

  const u32x4* abase = Ap + (size_t)mt * KT * 2048;
  const u32x4* bbase = Bp + (size_t)(e * NT + nt) * KT * 2048;

  auto stageA = [&](int Hs) {
    const int t = Hs >> 1, k32 = Hs & 1, s = Hs & 3;
    const u32x4* sa = abase + (size_t)t * 2048 + k32 * 1024;
    gld_lds16(sa + (wv * 2 + 0) * 64 + lane, &AsR[s * 1024 + (wv * 2 + 0) * 64]);
    gld_lds16(sa + (wv * 2 + 1) * 64 + lane, &AsR[s * 1024 + (wv * 2 + 1) * 64]);
  };
  auto stageB = [&](int Hs) {
    const int t = Hs >> 1, k32 = Hs & 1, s = Hs & 3;
    const u32x4* sb = bbase + (size_t)t * 2048 + k32 * 1024;
    gld_lds16(sb + (wv * 2 + 0) * 64 + lane, &BsR[s * 1024 + (wv * 2 + 0) * 64]);
    gld_lds16(sb + (wv * 2 + 1) * 64 + lane, &BsR[s * 1024 + (wv * 2 + 1) * 64]);
  };

  f32x4 acc[8][4] = {};
  const int NH = 2 * KT;

  stageA(0); stageB(0); stageA(1); stageB(1); stageA(2); stageB(2);  // 12 in flight

  for (int H = 0; H < NH; ++H) {
    const int rem = NH - 1 - H;
    if (rem >= 2)      asm volatile("s_waitcnt vmcnt(8)" ::: "memory");
    else if (rem == 1) asm volatile("s_waitcnt vmcnt(4)" ::: "memory");
    else               asm volatile("s_waitcnt vmcnt(0)" ::: "memory");
    __builtin_amdgcn_sched_barrier(0);
    __builtin_amdgcn_s_barrier();     // slab H complete in all waves; H-1 readers done
    __builtin_amdgcn_sched_barrier(0);
    const u32x4* Ah = AsR + (H & 3) * 1024;
    const u32x4* Bh = BsR + (H & 3) * 1024;
    const bool st = (H + 3 < NH);
    // ---- phase 0: stage A of H+3, read b[0..3]+a[0..3], 16 MFMA
    if (st) stageA(H + 3);
    __builtin_amdgcn_sched_barrier(0);
    s16x8 a[4], b[4];
#pragma unroll
    for (int ni = 0; ni < 4; ++ni)
      b[ni] = __builtin_bit_cast(s16x8, Bh[(wn * 4 + ni) * 64 + lane]);
#pragma unroll
    for (int mi = 0; mi < 4; ++mi)
      a[mi] = __builtin_bit_cast(s16x8, Ah[(wm * 8 + mi) * 64 + lane]);
    __builtin_amdgcn_s_setprio(1);
#pragma unroll
    for (int mi = 0; mi < 4; ++mi)
#pragma unroll
      for (int ni = 0; ni < 4; ++ni)
        acc[mi][ni] = __builtin_amdgcn_mfma_f32_16x16x32_bf16(a[mi], b[ni], acc[mi][ni], 0, 0, 0);
    __builtin_amdgcn_s_setprio(0);
    __builtin_amdgcn_sched_barrier(0);
    // ---- phase 1: stage B of H+3, read a[4..7], 16 MFMA
    if (st) stageB(H + 3);
    __builtin_amdgcn_sched_barrier(0);
#pragma unroll
    for (int mi = 0; mi < 4; ++mi)
      a[mi] = __builtin_bit_cast(s16x8, Ah[(wm * 8 + 4 + mi) * 64 + lane]);
    __builtin_amdgcn_s_setprio(1);
#pragma unroll
    for (int mi = 0; mi < 4; ++mi)
#pragma unroll
      for (int ni = 0; ni < 4; ++ni)
        acc[4 + mi][ni] = __builtin_amdgcn_mfma_f32_16x16x32_bf16(a[mi], b[ni], acc[4 + mi][ni], 0, 0, 0);
    __builtin_amdgcn_s_setprio(0);
  }

  __syncthreads();                    // all reads done; LDS free for epilogue

  // ---- epilogue: bias(+GELU)+f2bf scatter into LDS, then linear/coalesced out
  u16* cimg = (u16*)LB;
  const int rbase = ((lane >> 4) << 2);
  const int c16 = lane & 15;
  float bv[4];
#pragma unroll
  for (int ni = 0; ni < 4; ++ni)
    bv[ni] = bias[(size_t)e * Nfull + nt * 256 + wn * 64 + ni * 16 + c16];
#pragma unroll
  for (int mi = 0; mi < 8; ++mi)
#pragma unroll
    for (int ni = 0; ni < 4; ++ni)
#pragma unroll
      for (int r = 0; r < 4; ++r) {
        const int row = wm * 128 + mi * 16 + rbase + r;
        const int col = wn * 64 + ni * 16 + c16;
        float v = acc[mi][ni][r] + bv[ni];
        if (MODE) {
          v = 0.5f * v * (1.0f + erff(v * 0.70710678118654752f));
          const int k = col & 63;
          const int ent = (col >> 6) * 2048
                        + ((k >> 5) * 16 + (row >> 4)) * 64
                        + ((k >> 3) & 3) * 16 + (row & 15);
          cimg[ent * 8 + (k & 7)] = f2bf(v);
        } else {
          const int ch = col >> 3;
          cimg[row * 256 + ((ch ^ (row & 31)) << 3) + (col & 7)] = f2bf(v);
        }
      }
  __syncthreads();
  if (MODE) {
    // 4 GEMM2 A-image tiles (kt2 = nt*4 .. nt*4+3), 128KB linear
    u32x4* outp = (u32x4*)Cout + ((size_t)mt * KT2 + nt * 4) * 2048;
#pragma unroll
    for (int c = 0; c < 16; ++c) {
      const int idx = c * 512 + tid;
      outp[idx] = LB[idx];
    }
  } else {
    // row-major: 32 lanes per row, 512B contiguous
#pragma unroll
    for (int c = 0; c < 16; ++c) {
      const int cid = c * 512 + tid;
      const int row = cid >> 5, ch = cid & 31;
      *(u32x4*)&Cout[(size_t)(mt * BM + row) * DMODEL + nt * 256 + ch * 8]
          = LB[row * 32 + (ch ^ (row & 31))];
    }
  }
}

// ---------------- combine (top-2 weighted) + residual + LayerNorm ----------------
__global__ void k_combine_ln(const float* __restrict__ x, const u16* __restrict__ y,
                             const int* __restrict__ token_slot, const float* __restrict__ top_w,
                             const float* __restrict__ gamma, const float* __restrict__ beta,
                             float* __restrict__ out) {
  int t = blockIdx.x, tid = threadIdx.x;
  int s0 = token_slot[2 * t], s1 = token_slot[2 * t + 1];
  float w0 = top_w[2 * t], w1 = top_w[2 * t + 1];
  float4 xv = ((const float4*)(x + (size_t)t * DMODEL))[tid];
  uint2 a = ((const uint2*)(y + (size_t)s0 * DMODEL))[tid];
  uint2 b = ((const uint2*)(y + (size_t)s1 * DMODEL))[tid];
  float r0 = xv.x + w0 * bf2f(a.x & 0xffffu) + w1 * bf2f(b.x & 0xffffu);
  float r1 = xv.y + w0 * bf2f(a.x >> 16)     + w1 * bf2f(b.x >> 16);
  float r2 = xv.z + w0 * bf2f(a.y & 0xffffu) + w1 * bf2f(b.y & 0xffffu);
  float r3 = xv.w + w0 * bf2f(a.y >> 16)     + w1 * bf2f(b.y >> 16);
  float s  = r0 + r1 + r2 + r3;
  float sq = r0 * r0 + r1 * r1 + r2 * r2 + r3 * r3;
#pragma unroll
  for (int off = 32; off; off >>= 1) { s += __shfl_down(s, off); sq += __shfl_down(sq, off); }
  __shared__ float rs[4], rq[4];
  __shared__ float mu_s, rsig_s;
  int w = tid >> 6;
  if ((tid & 63) == 0) { rs[w] = s; rq[w] = sq; }
  __syncthreads();
  if (tid == 0) {
    float S = rs[0] + rs[1] + rs[2] + rs[3];
    float Q = rq[0] + rq[1] + rq[2] + rq[3];
    float mu  = S * (1.0f / DMODEL);
    float var = Q * (1.0f / DMODEL) - mu * mu;
    mu_s = mu; rsig_s = rsqrtf(var + 1e-5f);
  }
  __syncthreads();
  float mu = mu_s, rsig = rsig_s;
  float4 gv = ((const float4*)gamma)[tid];
  float4 bv = ((const float4*)beta)[tid];
  float4 o;
  o.x = (r0 - mu) * rsig * gv.x + bv.x;
  o.y = (r1 - mu) * rsig * gv.y + bv.y;
  o.z = (r2 - mu) * rsig * gv.z + bv.z;
  o.w = (r3 - mu) * rsig * gv.w + bv.w;
  ((float4*)(out + (size_t)t * DMODEL))[tid] = o;
}

// ---------------- launch ----------------
extern "C" void kernel_launch(void* const* d_in, const int* in_sizes, int n_in,
                              void* d_out, int out_size, void* d_ws, size_t ws_size,
                              hipStream_t stream) {
  const float* x     = (const float*)d_in[0];
  const float* Wg    = (const float*)d_in[1];
  const float* bg    = (const float*)d_in[2];
  const float* W1    = (const float*)d_in[3];
  const float* b1    = (const float*)d_in[4];
  const float* W2    = (const float*)d_in[5];
  const float* b2    = (const float*)d_in[6];
  const float* gamma = (const float*)d_in[7];
  const float* beta  = (const float*)d_in[8];
  float* out = (float*)d_out;

  // workspace (~193MB): Bp2 aliases [Ap1|Bp1] (written after GEMM1 completes)
  char* ws = (char*)d_ws;
  const size_t szAp1 = (size_t)MAX_MT * KT1 * 2048 * 16;   // 20.97 MB
  const size_t szBp1 = (size_t)NEXP * DMODEL * HFF * 2;    // 67.1 MB
  u32x4* Ap1 = (u32x4*)ws;
  u32x4* Bp1 = (u32x4*)(ws + szAp1);
  u32x4* Bp2 = (u32x4*)ws;                                  // alias
  char* p = ws + szAp1 + szBp1;
  u32x4* hImg = (u32x4*)p; p += (size_t)MAX_MT * KT2 * 2048 * 16;   // 83.9 MB
  u16*   yb   = (u16*)p;   p += (size_t)MAX_MT * BM * DMODEL * 2;   // 21.0 MB
  int*   meta = (int*)p;
  int*   counts      = meta;
  int*   cursor      = counts + 8;
  int*   poffset     = cursor + 8;
  int*   tok_of_slot = poffset + 8;
  int*   mtile_e     = tok_of_slot + MAX_MT * BM;
  int*   token_slot  = mtile_e + MAX_MT;
  int*   top_idx     = token_slot + 2 * NTOK;
  float* top_w       = (float*)(top_idx + 2 * NTOK);
  (void)ws_size; (void)in_sizes; (void)n_in; (void)out_size;

  // zero counts/cursor/poffset + tok_of_slot (pad rows -> token 0)
  hipMemsetAsync(meta, 0, (size_t)(24 + MAX_MT * BM) * 4, stream);

  k_gating<<<NTOK, 256, 0, stream>>>(x, Wg, bg, top_idx, top_w, counts);
  k_offsets<<<1, 1, 0, stream>>>(counts, poffset, mtile_e);
  k_scatter<<<NTOK / 256, 256, 0, stream>>>(top_idx, poffset, cursor, tok_of_slot, token_slot);

  // W1 [8][1024][4096] -> Bp1 (NT=16, KT=16), 2048 blocks
  k_prearrange<<<NEXP * (HFF / 256) * KT1, 256, 0, stream>>>(W1, Bp1, DMODEL, HFF, HFF / 256, KT1);
  // gathered token images (40 x 16 = 640 blocks)
  k_arrange_a<<<MAX_MT * KT1, 256, 0, stream>>>(x, tok_of_slot, mtile_e, Ap1);

  // GEMM1: 16 nt x 40 mt = 640 blocks; GELU; writes h as GEMM2 A-images
  k_gemm<1><<<(HFF / 256) * MAX_MT, 512, 0, stream>>>(
      Ap1, Bp1, b1, HFF, HFF / 256, KT1, mtile_e, (u16*)hImg);

  // W2 [8][4096][1024] -> Bp2 (NT=4, KT=64) — after GEMM1 (aliases Ap1/Bp1)
  k_prearrange<<<NEXP * (DMODEL / 256) * KT2, 256, 0, stream>>>(W2, Bp2, HFF, DMODEL, DMODEL / 256, KT2);

  // GEMM2: 4 nt x 40 mt = 160 blocks; writes yb row-major
  k_gemm<0><<<(DMODEL / 256) * MAX_MT, 512, 0, stream>>>(
      hImg, Bp2, b2, DMODEL, DMODEL / 256, KT2, mtile_e, yb);

  k_combine_ln<<<NTOK, 256, 0, stream>>>(x, yb, token_slot, top_w, gamma, beta, out);
}